// Round 10
// baseline (448.081 us; speedup 1.0000x reference)
//
#include <hip/hip_runtime.h>

#define B_ 32
#define C_ 512
#define HW_ 3136
#define KF_ 512
#define KM_ 48
#define NCL_ 5

typedef __attribute__((ext_vector_type(8))) short short8;
typedef __attribute__((ext_vector_type(4))) short short4v;
typedef __attribute__((ext_vector_type(4))) float floatx4;
typedef unsigned int u32;
typedef u32 __attribute__((address_space(1))) gu32;
typedef u32 __attribute__((address_space(3))) lu32;

__device__ __forceinline__ unsigned short f2bf(float f) {
    union { float f; unsigned u; } v; v.f = f;
    unsigned r = v.u + 0x7FFFu + ((v.u >> 16) & 1u);
    return (unsigned short)(r >> 16);
}
__device__ __forceinline__ float bf2f(unsigned short u) {
    union { unsigned u; float f; } v; v.u = ((unsigned)u) << 16;
    return v.f;
}
__device__ __forceinline__ void gl2lds16(const void* g, void* l) {
    __builtin_amdgcn_global_load_lds((const gu32*)g, (lu32*)l, 16, 0, 0);
}
__device__ __forceinline__ void gl2lds4(const void* g, void* l) {
    __builtin_amdgcn_global_load_lds((const gu32*)g, (lu32*)l, 4, 0, 0);
}

// ---- K0: normalize conv weights -> bf16 wn; clutter -> ckb (clip+L1, bf16,
//      padded to 16 rows, rows >= NCL_ zeroed)
__global__ __launch_bounds__(64) void prep_kernel(const float* __restrict__ w,
                                                  const float* __restrict__ cl,
                                                  unsigned short* __restrict__ wn,
                                                  unsigned short* __restrict__ ckb) {
    int bid = blockIdx.x, t = threadIdx.x;
    if (bid < KF_) {
        const float* row = w + (size_t)bid * C_;
        float ss = 0.f;
        float x[8];
#pragma unroll
        for (int j = 0; j < 8; ++j) { x[j] = row[t * 8 + j]; ss += x[j] * x[j]; }
        for (int m = 32; m >= 1; m >>= 1) ss += __shfl_xor(ss, m);
        float inv = 1.f / sqrtf(ss);
#pragma unroll
        for (int j = 0; j < 8; ++j) wn[(size_t)bid * C_ + t * 8 + j] = f2bf(x[j] * inv);
    } else {
        int n = bid - KF_;
        if (n >= 16) return;
        if (n < NCL_) {
            const float* row = cl + (size_t)n * KF_;
            float s = 0.f;
            float v[8];
#pragma unroll
            for (int j = 0; j < 8; ++j) {
                float x = row[t * 8 + j];
                x = fminf(fmaxf(x, 0.f), 1.f);
                v[j] = x; s += x;
            }
            for (int m = 32; m >= 1; m >>= 1) s += __shfl_xor(s, m);
            float inv = 1.f / fmaxf(s, 1e-12f);
#pragma unroll
            for (int j = 0; j < 8; ++j) ckb[(size_t)n * KF_ + t * 8 + j] = f2bf(v[j] * inv);
        } else {
#pragma unroll
            for (int j = 0; j < 8; ++j) ckb[(size_t)n * KF_ + t * 8 + j] = 0;
        }
    }
}

// ---- K1: streaming pass: vgg -> xnt (raw bf16, [b*HW+p][c]), invn, vgg copy
__global__ __launch_bounds__(512) void xprep_kernel(const float* __restrict__ vgg,
                                                    unsigned short* __restrict__ xnt,
                                                    float* __restrict__ invn,
                                                    float* __restrict__ out_vgg,
                                                    int write_vgg) {
    int pt = blockIdx.x, b = blockIdx.y;
    int tid = threadIdx.x;
    int px = tid & 63, cq = tid >> 6;
    __shared__ __align__(16) unsigned short tile[64][512];
    __shared__ float ssp[8][64];
    const float* vcol = vgg + (size_t)b * C_ * HW_ + pt * 64 + px;
    float* ovcol = out_vgg + (size_t)b * C_ * HW_ + pt * 64 + px;

    float ss = 0.f;
#pragma unroll
    for (int j = 0; j < 16; ++j) {
        int c0 = cq * 64 + j * 4;
        float x0 = vcol[(size_t)(c0 + 0) * HW_];
        float x1 = vcol[(size_t)(c0 + 1) * HW_];
        float x2 = vcol[(size_t)(c0 + 2) * HW_];
        float x3 = vcol[(size_t)(c0 + 3) * HW_];
        ss += x0 * x0 + x1 * x1 + x2 * x2 + x3 * x3;
        short4v pk;
        pk[0] = (short)f2bf(x0); pk[1] = (short)f2bf(x1);
        pk[2] = (short)f2bf(x2); pk[3] = (short)f2bf(x3);
        *(short4v*)&tile[px][c0] = pk;
        if (write_vgg) {
            ovcol[(size_t)(c0 + 0) * HW_] = x0;
            ovcol[(size_t)(c0 + 1) * HW_] = x1;
            ovcol[(size_t)(c0 + 2) * HW_] = x2;
            ovcol[(size_t)(c0 + 3) * HW_] = x3;
        }
    }
    ssp[cq][px] = ss;
    __syncthreads();
    if (tid < 64) {
        float s = 0.f;
#pragma unroll
        for (int q = 0; q < 8; ++q) s += ssp[q][tid];
        float n = sqrtf(s);
        invn[(size_t)b * HW_ + pt * 64 + tid] = (n == 0.f) ? 1.f : 1.f / n;
    }
    __syncthreads();
    int row = tid >> 3, ch = tid & 7;
    unsigned short* orow = xnt + ((size_t)b * HW_ + pt * 64 + row) * 512;
#pragma unroll
    for (int j = 0; j < 8; ++j) {
        int c8 = (ch + 8 * j) * 8;
        *(short8*)(orow + c8) = *(const short8*)&tile[row][c8];
    }
}

// ---- K1b: mm fp32 -> clipped bf16 in chunked layout + csum partials.
// mmb[((m*32+ch)*3136+px)*16 + kin]; csumg[kh*48*3136 + m*3136 + px] (2 halves).
__global__ __launch_bounds__(448) void mmprep_kernel(const float* __restrict__ mm,
                                                     unsigned short* __restrict__ mmb,
                                                     float* __restrict__ csumg) {
    int m = blockIdx.x;
    int kh = blockIdx.z;
    int px = blockIdx.y * 448 + threadIdx.x;
    const float* src = mm + ((size_t)m * KF_ + kh * 256) * HW_ + px;
    unsigned short* dst = mmb + ((size_t)(m * 32 + kh * 16) * HW_ + px) * 16;
    float cs = 0.f;
#pragma unroll 1
    for (int ch = 0; ch < 16; ++ch) {
        short8 lo, hi;
#pragma unroll
        for (int kin = 0; kin < 8; ++kin) {
            float x = src[(size_t)(ch * 16 + kin) * HW_];
            x = fminf(fmaxf(x, 0.f), 1.f);
            cs += x; lo[kin] = (short)f2bf(x);
        }
#pragma unroll
        for (int kin = 8; kin < 16; ++kin) {
            float x = src[(size_t)(ch * 16 + kin) * HW_];
            x = fminf(fmaxf(x, 0.f), 1.f);
            cs += x; hi[kin - 8] = (short)f2bf(x);
        }
        *(short8*)(dst + (size_t)ch * HW_ * 16) = lo;
        *(short8*)(dst + (size_t)ch * HW_ * 16 + 8) = hi;
    }
    csumg[(size_t)kh * 48 * HW_ + (size_t)m * HW_ + px] = cs;
}

// ---- K2: pure GEMM act = exp(30*(xnt.wn)*invn), counted-vmcnt dbuf pipeline.
// Sync: barrier(WAR) -> issue next stage -> own vmcnt -> barrier(RAW) -> compute.
__global__ __launch_bounds__(512) void gemm_act_kernel(const unsigned short* __restrict__ xnt,
                                                       const unsigned short* __restrict__ wn,
                                                       const float* __restrict__ invn,
                                                       unsigned short* __restrict__ act) {
    int wg = blockIdx.x;
    int swz = (wg & 7) * 392 + (wg >> 3);   // 3136 = 8*392, bijective
    int pt = swz >> 2, ft = swz & 3;
    int tid = threadIdx.x, lane = tid & 63;
    int wid = tid >> 6;
    int li = lane & 15, q = lane >> 4;
    int wm = wid & 1, wq = wid >> 1;

    __shared__ __align__(16) unsigned short a_lds[2][128 * 64];
    __shared__ __align__(16) unsigned short b_lds[2][128 * 64];
    __shared__ float inv_l[128];
    if (tid < 128) inv_l[tid] = invn[(size_t)pt * 128 + tid];

    const unsigned short* ga = wn + ((size_t)ft * 128 + (tid >> 3)) * 512 + (tid & 7) * 8;
    const unsigned short* gb = xnt + ((size_t)pt * 128 + (tid >> 3)) * 512 + (tid & 7) * 8;
    int ldst = tid * 8;

    floatx4 acc[4][2] = {};

#pragma unroll
    for (int i = 0; i < 2; ++i) {
        gl2lds16(ga + (size_t)i * 64 * 512, &a_lds[0][ldst + i * 4096]);
        gl2lds16(gb + (size_t)i * 64 * 512, &b_lds[0][ldst + i * 4096]);
    }

#pragma unroll 1
    for (int s = 0; s < 8; ++s) {
        __builtin_amdgcn_s_barrier();   // WAR: prior reads of next buf done
        if (s < 7) {
            int nb = (s + 1) & 1;
#pragma unroll
            for (int i = 0; i < 2; ++i) {
                gl2lds16(ga + (size_t)i * 64 * 512 + (s + 1) * 64, &a_lds[nb][ldst + i * 4096]);
                gl2lds16(gb + (size_t)i * 64 * 512 + (s + 1) * 64, &b_lds[nb][ldst + i * 4096]);
            }
            asm volatile("s_waitcnt vmcnt(4)" ::: "memory");  // own stage-s done
        } else {
            asm volatile("s_waitcnt vmcnt(0)" ::: "memory");
        }
        __builtin_amdgcn_sched_barrier(0);
        __builtin_amdgcn_s_barrier();   // RAW: ALL waves' stage-s loads done
        int buf = s & 1;
#pragma unroll
        for (int k2 = 0; k2 < 2; ++k2) {
            short8 af[4], bfr[2];
#pragma unroll
            for (int i = 0; i < 4; ++i)
                af[i] = *(const short8*)&a_lds[buf][(wm * 64 + i * 16 + li) * 64 + k2 * 32 + q * 8];
#pragma unroll
            for (int j = 0; j < 2; ++j)
                bfr[j] = *(const short8*)&b_lds[buf][(wq * 32 + j * 16 + li) * 64 + k2 * 32 + q * 8];
#pragma unroll
            for (int i = 0; i < 4; ++i)
#pragma unroll
                for (int j = 0; j < 2; ++j)
                    acc[i][j] = __builtin_amdgcn_mfma_f32_16x16x32_bf16(af[i], bfr[j], acc[i][j], 0, 0, 0);
        }
    }

#pragma unroll
    for (int j = 0; j < 2; ++j) {
        int px = wq * 32 + j * 16 + li;
        float inv = inv_l[px];
        size_t row_g = (size_t)pt * 128 + px;
#pragma unroll
        for (int i = 0; i < 4; ++i) {
            int chn = ft * 8 + wm * 4 + i;
            short4v pk;
#pragma unroll
            for (int r = 0; r < 4; ++r) {
                float cv = acc[i][j][r] * inv;
                float a = cv > 0.f ? __expf(30.f * cv) : 0.f;
                pk[r] = (short)f2bf(a);
            }
            *(short4v*)(act + ((size_t)chn * 100352 + row_g) * 16 + q * 4) = pk;
        }
    }
}

// ---- K4 v3: fg from bf16 act + bf16 mmb, 3-buffer counted-vmcnt pipeline.
// 196 blocks x 512 thr (8 waves, 2 px each). 32 stages of K16.
#define FG_ABUF 16640                   // 16*1040
#define FG_MBUF 24960                   // 24*1040
#define FG_BUF  (FG_ABUF + FG_MBUF)     // 41600
#define FG_OFF_CSUM (3 * FG_BUF)        // 124800
#define FG_OFF_PMS  (FG_OFF_CSUM + 3072)
#define FG_OFF_CKB  (FG_OFF_PMS + 6144)
// total = 124800 + 3072 + 6144 + 16640 = 150656
__global__ __launch_bounds__(512) void fg2_kernel(const unsigned short* __restrict__ act,
                                                  const unsigned short* __restrict__ mmb,
                                                  const float* __restrict__ csumg,
                                                  const unsigned short* __restrict__ ckb,
                                                  float* __restrict__ pm) {
    __shared__ __align__(16) unsigned char L[150656];
    float* csum_s = (float*)(L + FG_OFF_CSUM);            // [48][16]
    float* pms    = (float*)(L + FG_OFF_PMS);             // [48][32]
    unsigned short* ckbl = (unsigned short*)(L + FG_OFF_CKB);  // [16][520]

    int p0 = blockIdx.x * 16;
    int tid = threadIdx.x;
    int lane = tid & 63, w = tid >> 6;
    int li = lane & 15, q = lane >> 4;

    for (int i = tid; i < 1536; i += 512) pms[i] = 0.f;
    for (int i = tid; i < 768; i += 512) {      // FIX: grid-stride (512 thr < 768)
        int m = i >> 4, pp = i & 15;
        size_t idx = (size_t)m * HW_ + p0 + pp;
        csum_s[i] = csumg[idx] + csumg[(size_t)48 * HW_ + idx];
    }
    {
        int row = tid >> 5, cg = tid & 31;
        *(short8*)&ckbl[row * 520 + cg * 16] = *(const short8*)(ckb + row * 512 + cg * 16);
        *(short8*)&ckbl[row * 520 + cg * 16 + 8] = *(const short8*)(ckb + row * 512 + cg * 16 + 8);
    }
    __syncthreads();   // LDS init visible to all before pipeline starts

    // per-lane global offsets (b/m-sub = lane>>5, px = (lane>>1)&15, kh = lane&1)
    size_t a_lane = ((size_t)(lane >> 5) * HW_ + p0 + ((lane >> 1) & 15)) * 16 + (lane & 1) * 8;
    size_t m_lane = (size_t)(lane >> 5) * 1605632 + ((size_t)p0 + ((lane >> 1) & 15)) * 16 + (lane & 1) * 8;

    auto stage = [&](int s) {
        unsigned char* ab = L + (s % 3) * FG_BUF;
        unsigned char* mb = ab + FG_ABUF;
        const unsigned short* as = act + (size_t)s * 1605632 + a_lane;
        const unsigned short* ms = mmb + (size_t)s * 50176 + m_lane;
#pragma unroll
        for (int t = 0; t < 2; ++t) {
            int j = w + t * 8;
            gl2lds16(as + (size_t)(2 * j) * (HW_ * 16), ab + j * 1040);
        }
#pragma unroll
        for (int t = 0; t < 3; ++t) {
            int j = w + t * 8;
            gl2lds16(ms + (size_t)(2 * j) * 1605632, mb + j * 1040);
        }
    };

    short8 fa[2][2] = {};
    short8 fm[2][3] = {};
    short8 fck = {};
    floatx4 acc[2][3][2] = {};
    floatx4 abg[2][2] = {};

    stage(0);
    stage(1);

#pragma unroll 2
    for (int s = 0; s < 32; ++s) {
        __builtin_amdgcn_s_barrier();   // WAR: prior reads of buf (s+2)%3 done
        if (s < 30) {
            stage(s + 2);
            asm volatile("s_waitcnt vmcnt(10)" ::: "memory");  // own stage-s done
        } else if (s == 30) {
            asm volatile("s_waitcnt vmcnt(5)" ::: "memory");
        } else {
            asm volatile("s_waitcnt vmcnt(0)" ::: "memory");
        }
        __builtin_amdgcn_sched_barrier(0);
        __builtin_amdgcn_s_barrier();   // RAW: ALL waves' stage-s loads landed
        const unsigned char* ab = L + (s % 3) * FG_BUF;
        const unsigned char* mb = ab + FG_ABUF;
        if ((q >> 1) == (s & 1)) {
#pragma unroll
            for (int e = 0; e < 2; ++e) {
                int pp = w * 2 + e;
#pragma unroll
                for (int bf = 0; bf < 2; ++bf)
                    fa[e][bf] = *(const short8*)(ab + (bf * 8 + (li >> 1)) * 1040 +
                                                 ((li & 1) * 16 + pp) * 32 + (q & 1) * 16);
#pragma unroll
                for (int mf = 0; mf < 3; ++mf)
                    fm[e][mf] = *(const short8*)(mb + (mf * 8 + (li >> 1)) * 1040 +
                                                 ((li & 1) * 16 + pp) * 32 + (q & 1) * 16);
            }
            fck = *(const short8*)&ckbl[li * 520 + s * 16 + (q & 1) * 8];
        }
        if (s & 1) {
#pragma unroll
            for (int e = 0; e < 2; ++e) {
#pragma unroll
                for (int mf = 0; mf < 3; ++mf) {
                    acc[e][mf][0] = __builtin_amdgcn_mfma_f32_16x16x32_bf16(fm[e][mf], fa[e][0], acc[e][mf][0], 0, 0, 0);
                    acc[e][mf][1] = __builtin_amdgcn_mfma_f32_16x16x32_bf16(fm[e][mf], fa[e][1], acc[e][mf][1], 0, 0, 0);
                }
                abg[e][0] = __builtin_amdgcn_mfma_f32_16x16x32_bf16(fck, fa[e][0], abg[e][0], 0, 0, 0);
                abg[e][1] = __builtin_amdgcn_mfma_f32_16x16x32_bf16(fck, fa[e][1], abg[e][1], 0, 0, 0);
            }
        }
    }

    // epilogue
#pragma unroll
    for (int e = 0; e < 2; ++e) {
        int pp = w * 2 + e;
#pragma unroll
        for (int bf = 0; bf < 2; ++bf) {
            int b = bf * 16 + li;
            float v = -1e30f;
#pragma unroll
            for (int r = 0; r < 4; ++r) v = fmaxf(v, logf(abg[e][bf][r] * 0.6f + 1e-10f));
            v = fmaxf(v, __shfl_xor(v, 16));
            v = fmaxf(v, __shfl_xor(v, 32));
            float bgv = v;
#pragma unroll
            for (int mf = 0; mf < 3; ++mf)
#pragma unroll
                for (int r = 0; r < 4; ++r) {
                    int m = mf * 16 + q * 4 + r;
                    float inv = 1.f / fmaxf(csum_s[m * 16 + pp], 1e-12f);
                    float fv = fmaxf(logf(acc[e][mf][bf][r] * inv * 0.4f + 1e-10f), bgv);
                    atomicAdd(&pms[m * 32 + b], fv);
                }
        }
    }
    __syncthreads();
    {
        int i3 = tid * 3;
#pragma unroll
        for (int j = 0; j < 3; ++j) {
            int i = i3 + j;
            int m = i >> 5, b = i & 31;
            atomicAdd(&pm[(size_t)b * KM_ + m], pms[i]);
        }
    }
}

// ---- K4 fallback (R7 fg): mm fp32 direct, internal csum, fused ck.
#define MMBUF 50112
#define ACTBUF 16640
#define OFF_ACT0 (2*MMBUF)
#define OFF_CSUM (2*MMBUF + 2*ACTBUF)
#define OFF_PMS  (OFF_CSUM + 3072)
#define OFF_CKB  (OFF_PMS + 6144)
__global__ __launch_bounds__(1024) void fg_fb_kernel(const unsigned short* __restrict__ act,
                                                     const float* __restrict__ mm,
                                                     const unsigned short* __restrict__ ckb,
                                                     float* __restrict__ pm) {
    __shared__ __align__(16) unsigned char L[OFF_CKB + 16 * 520 * 2];
    float* csum_s = (float*)(L + OFF_CSUM);
    float* pms    = (float*)(L + OFF_PMS);
    unsigned short* ckbl = (unsigned short*)(L + OFF_CKB);

    int p0 = blockIdx.x * 16;
    int tid = threadIdx.x;
    int lane = tid & 63, wid = tid >> 6;
    int li = lane & 15, q = lane >> 4;
    int pp = wid;
    int w3 = wid * 3;

    for (int i = tid; i < 1536; i += 1024) pms[i] = 0.f;
    {
        int row = tid >> 6, cg = tid & 63;
        *(short8*)&ckbl[row * 520 + cg * 8] = *(const short8*)(ckb + row * 512 + cg * 8);
    }

    const float* mm_src = mm + ((size_t)(w3 * KF_) + (size_t)(lane >> 4)) * HW_ + p0 + (lane & 15);
    const unsigned short* act_src = act +
        ((size_t)(2 * wid + (lane >> 5)) * HW_ + p0 + ((lane >> 1) & 15)) * 16 + (lane & 1) * 8;

    auto stage = [&](int s) {
        unsigned char* mb = L + (s & 1) * MMBUF;
        unsigned char* ab = L + OFF_ACT0 + (s & 1) * ACTBUF;
        const float* ms = mm_src + (size_t)s * 16 * HW_;
#pragma unroll
        for (int jj = 0; jj < 12; ++jj)
            gl2lds4(ms + (size_t)((jj >> 2) * KF_ + (jj & 3) * 4) * HW_,
                    mb + (w3 + (jj >> 2)) * 1044 + (jj & 3) * 256);
        gl2lds16(act_src + (size_t)s * 100352 * 16, ab + wid * 1040);
    };

    short8 fa[2] = {};
    short8 fmA[3] = {};
    short8 fck = {};
    floatx4 acc[3][2] = {};
    floatx4 accbg[2] = {};
    float csp[3] = {0.f, 0.f, 0.f};

    stage(0);
    __syncthreads();

#pragma unroll 2
    for (int s = 0; s < 32; ++s) {
        if (s < 31) stage(s + 1);
        const unsigned char* mc = L + (s & 1) * MMBUF;
        const unsigned char* ac = L + OFF_ACT0 + (s & 1) * ACTBUF;
        if ((q >> 1) == (s & 1)) {
#pragma unroll
            for (int bf = 0; bf < 2; ++bf)
                fa[bf] = *(const short8*)(ac + (bf * 8 + (li >> 1)) * 1040 +
                                          ((li & 1) * 16 + pp) * 32 + (q & 1) * 16);
#pragma unroll
            for (int mf = 0; mf < 3; ++mf) {
                const unsigned char* arow = mc + (mf * 16 + li) * 1044 + (q & 1) * 512 + pp * 4;
                short8 pk;
                float s0 = 0.f;
#pragma unroll
                for (int j = 0; j < 8; ++j) {
                    float x = *(const float*)(arow + j * 64);
                    x = fminf(fmaxf(x, 0.f), 1.f);
                    s0 += x;
                    pk[j] = (short)f2bf(x);
                }
                csp[mf] += s0;
                fmA[mf] = pk;
            }
            fck = *(const short8*)&ckbl[li * 520 + s * 16 + (q & 1) * 8];
        }
        if (s & 1) {
#pragma unroll
            for (int mf = 0; mf < 3; ++mf) {
                acc[mf][0] = __builtin_amdgcn_mfma_f32_16x16x32_bf16(fmA[mf], fa[0], acc[mf][0], 0, 0, 0);
                acc[mf][1] = __builtin_amdgcn_mfma_f32_16x16x32_bf16(fmA[mf], fa[1], acc[mf][1], 0, 0, 0);
            }
            accbg[0] = __builtin_amdgcn_mfma_f32_16x16x32_bf16(fck, fa[0], accbg[0], 0, 0, 0);
            accbg[1] = __builtin_amdgcn_mfma_f32_16x16x32_bf16(fck, fa[1], accbg[1], 0, 0, 0);
        }
        __syncthreads();
    }

#pragma unroll
    for (int mf = 0; mf < 3; ++mf) {
        float v = csp[mf];
        v += __shfl_xor(v, 16);
        v += __shfl_xor(v, 32);
        if (q == 0) csum_s[(mf * 16 + li) * 16 + pp] = v;
    }

    float bgv[2];
#pragma unroll
    for (int bf = 0; bf < 2; ++bf) {
        float v = -1e30f;
#pragma unroll
        for (int r = 0; r < 4; ++r) v = fmaxf(v, logf(accbg[bf][r] * 0.6f + 1e-10f));
        v = fmaxf(v, __shfl_xor(v, 16));
        v = fmaxf(v, __shfl_xor(v, 32));
        bgv[bf] = v;
    }
    __syncthreads();

#pragma unroll
    for (int mf = 0; mf < 3; ++mf)
#pragma unroll
        for (int bf = 0; bf < 2; ++bf) {
            int b = bf * 16 + li;
#pragma unroll
            for (int r = 0; r < 4; ++r) {
                int m = mf * 16 + q * 4 + r;
                float inv = 1.f / fmaxf(csum_s[m * 16 + pp], 1e-12f);
                float v = fmaxf(logf(acc[mf][bf][r] * inv * 0.4f + 1e-10f), bgv[bf]);
                atomicAdd(&pms[m * 32 + b], v);
            }
        }
    __syncthreads();
    if (tid < 512) {
        int i3 = tid * 3;
#pragma unroll
        for (int j = 0; j < 3; ++j) {
            int i = i3 + j;
            int m = i >> 5, b = i & 31;
            atomicAdd(&pm[(size_t)b * KM_ + m], pms[i]);
        }
    }
}

// ---- K5: scores -> mix_likeli -> softmax
__global__ __launch_bounds__(64) void final_kernel(const float* __restrict__ pm,
                                                   float* __restrict__ out_soft,
                                                   float* __restrict__ out_ml) {
    int b = threadIdx.x;
    if (b >= B_) return;
    float ml[12];
#pragma unroll
    for (int c = 0; c < 12; ++c) {
        float s = -1e30f;
#pragma unroll
        for (int j = 0; j < 4; ++j) s = fmaxf(s, pm[(size_t)b * KM_ + c * 4 + j]);
        ml[c] = s / (float)HW_;
    }
    float z[12], zs = 0.f;
#pragma unroll
    for (int c = 0; c < 12; ++c) {
        float e = fminf(fmaxf(ml[c] * 2.f, -88.7f), 88.7f);
        z[c] = expf(e); zs += z[c];
    }
#pragma unroll
    for (int c = 0; c < 12; ++c) {
        out_soft[(size_t)b * 12 + c] = z[c] / zs;
        out_ml[(size_t)b * 12 + c] = ml[c];
    }
}

extern "C" void kernel_launch(void* const* d_in, const int* in_sizes, int n_in,
                              void* d_out, int out_size, void* d_ws, size_t ws_size,
                              hipStream_t stream) {
    const float* vgg = (const float*)d_in[0];
    const float* cw  = (const float*)d_in[1];
    const float* mmp = (const float*)d_in[2];
    const float* cl  = (const float*)d_in[3];
    float* out = (float*)d_out;
    char* ws = (char*)d_ws;

    unsigned short* wn   = (unsigned short*)(ws);              // 524288
    unsigned short* ckb  = (unsigned short*)(ws + 524288);     // 16384
    float* invn          = (float*)(ws + 540672);              // 401408
    float* pm            = (float*)(ws + 942080);              // 6144
    float* csumg         = (float*)(ws + 948224);              // 1204224
    unsigned short* xnt  = (unsigned short*)(ws + 2152448);    // 102760448
    unsigned short* mmb  = (unsigned short*)(ws + 104912896);  // 154140672
    const size_t MID_NEED = 104912896ull + 154140672ull;       // 259053568
    const size_t ACT_BYTES = (size_t)B_ * HW_ * KF_ * 2;       // 102760448

    hipMemsetAsync(pm, 0, (size_t)B_ * KM_ * sizeof(float), stream);
    prep_kernel<<<dim3(KF_ + 16), dim3(64), 0, stream>>>(cw, cl, wn, ckb);

    if (ws_size >= MID_NEED) {
        int act_in_ws = (ws_size >= MID_NEED + ACT_BYTES) ? 1 : 0;
        unsigned short* act = act_in_ws ? (unsigned short*)(ws + MID_NEED)
                                        : (unsigned short*)(out + 384);
        xprep_kernel<<<dim3(49, 32), dim3(512), 0, stream>>>(vgg, xnt, invn, out + 384, act_in_ws);
        mmprep_kernel<<<dim3(48, 7, 2), dim3(448), 0, stream>>>(mmp, mmb, csumg);
        gemm_act_kernel<<<dim3(3136), dim3(512), 0, stream>>>(xnt, wn, invn, act);
        fg2_kernel<<<dim3(196), dim3(512), 0, stream>>>(act, mmb, csumg, ckb, pm);
        final_kernel<<<1, 64, 0, stream>>>(pm, out, out + 384 + (size_t)B_ * C_ * HW_);
        if (!act_in_ws)
            hipMemcpyAsync(out + 384, vgg, (size_t)B_ * C_ * HW_ * sizeof(float),
                           hipMemcpyDeviceToDevice, stream);
    } else {
        // fallback: R7 structure (no mmprep)
        unsigned short* xnt2 = (unsigned short*)(ws + 948224);
        const size_t ACT_OFF = 948224 + 102760448;
        int big_ws = (ws_size >= ACT_OFF + ACT_BYTES) ? 1 : 0;
        unsigned short* act = big_ws ? (unsigned short*)(ws + ACT_OFF)
                                     : (unsigned short*)(out + 384);
        xprep_kernel<<<dim3(49, 32), dim3(512), 0, stream>>>(vgg, xnt2, invn, out + 384, big_ws);
        gemm_act_kernel<<<dim3(3136), dim3(512), 0, stream>>>(xnt2, wn, invn, act);
        fg_fb_kernel<<<dim3(196), dim3(1024), 0, stream>>>(act, mmp, ckb, pm);
        final_kernel<<<1, 64, 0, stream>>>(pm, out, out + 384 + (size_t)B_ * C_ * HW_);
        if (!big_ws)
            hipMemcpyAsync(out + 384, vgg, (size_t)B_ * C_ * HW_ * sizeof(float),
                           hipMemcpyDeviceToDevice, stream);
    }
}